// Round 1
// baseline (1560.179 us; speedup 1.0000x reference)
//
#include <hip/hip_runtime.h>
#include <hip/hip_bf16.h>

#define HD 256   // hidden dim H
#define LD 64    // latent dim L

// ---------------------------------------------------------------------------
// zero workspace (d_ws is poisoned to 0xAA before every timed call)
// ---------------------------------------------------------------------------
__global__ __launch_bounds__(256) void zero_ws(float* __restrict__ p, int n) {
  int i = blockIdx.x * 256 + threadIdx.x;
  int stride = gridDim.x * 256;
  for (; i < n; i += stride) p[i] = 0.0f;
}

// ---------------------------------------------------------------------------
// segment sum of two row-streams (tree_vecs, inter_vecs) with sorted segments.
// One wave owns a contiguous chunk of rows; lane i holds floats [4i,4i+4) of
// the 256-float row. Register-accumulate within a run of equal seg ids; flush
// with atomics only at boundaries.
// ---------------------------------------------------------------------------
__global__ __launch_bounds__(256) void seg_pair_sum(
    const float* __restrict__ va, const float* __restrict__ vb,
    const int* __restrict__ seg, int n, int rpw,
    float* __restrict__ sa, float* __restrict__ sb, float* __restrict__ cnt)
{
  int wid  = (blockIdx.x * 256 + threadIdx.x) >> 6;
  int lane = threadIdx.x & 63;
  int r0 = wid * rpw;
  if (r0 >= n) return;
  int r1 = min(r0 + rpw, n);

  float4 aa = make_float4(0.f, 0.f, 0.f, 0.f);
  float4 ab = make_float4(0.f, 0.f, 0.f, 0.f);
  int cur = seg[r0];
  float c = 0.f;

  for (int r = r0; r < r1; ++r) {
    int s = seg[r];
    if (s != cur) {
      float* pa = sa + (size_t)cur * HD + lane * 4;
      atomicAdd(pa + 0, aa.x); atomicAdd(pa + 1, aa.y);
      atomicAdd(pa + 2, aa.z); atomicAdd(pa + 3, aa.w);
      float* pb = sb + (size_t)cur * HD + lane * 4;
      atomicAdd(pb + 0, ab.x); atomicAdd(pb + 1, ab.y);
      atomicAdd(pb + 2, ab.z); atomicAdd(pb + 3, ab.w);
      if (lane == 0) atomicAdd(cnt + cur, c);
      aa = make_float4(0.f, 0.f, 0.f, 0.f);
      ab = make_float4(0.f, 0.f, 0.f, 0.f);
      c = 0.f;
      cur = s;
    }
    float4 xa = *reinterpret_cast<const float4*>(va + (size_t)r * HD + lane * 4);
    float4 xb = *reinterpret_cast<const float4*>(vb + (size_t)r * HD + lane * 4);
    aa.x += xa.x; aa.y += xa.y; aa.z += xa.z; aa.w += xa.w;
    ab.x += xb.x; ab.y += xb.y; ab.z += xb.z; ab.w += xb.w;
    c += 1.f;
  }
  float* pa = sa + (size_t)cur * HD + lane * 4;
  atomicAdd(pa + 0, aa.x); atomicAdd(pa + 1, aa.y);
  atomicAdd(pa + 2, aa.z); atomicAdd(pa + 3, aa.w);
  float* pb = sb + (size_t)cur * HD + lane * 4;
  atomicAdd(pb + 0, ab.x); atomicAdd(pb + 1, ab.y);
  atomicAdd(pb + 2, ab.z); atomicAdd(pb + 3, ab.w);
  if (lane == 0) atomicAdd(cnt + cur, c);
}

// ---------------------------------------------------------------------------
// anchor pooling: segment_sum(graph_vecs[anchor_idx], anchor_seg)
// ---------------------------------------------------------------------------
__global__ __launch_bounds__(256) void anchor_pool(
    const float* __restrict__ gv, const int* __restrict__ aidx,
    const int* __restrict__ aseg, int n, int rpw, float* __restrict__ pool)
{
  int wid  = (blockIdx.x * 256 + threadIdx.x) >> 6;
  int lane = threadIdx.x & 63;
  int r0 = wid * rpw;
  if (r0 >= n) return;
  int r1 = min(r0 + rpw, n);

  float4 acc = make_float4(0.f, 0.f, 0.f, 0.f);
  int cur = aseg[r0];

  for (int r = r0; r < r1; ++r) {
    int s = aseg[r];
    if (s != cur) {
      float* pp = pool + (size_t)cur * HD + lane * 4;
      atomicAdd(pp + 0, acc.x); atomicAdd(pp + 1, acc.y);
      atomicAdd(pp + 2, acc.z); atomicAdd(pp + 3, acc.w);
      acc = make_float4(0.f, 0.f, 0.f, 0.f);
      cur = s;
    }
    int gi = aidx[r];
    float4 x = *reinterpret_cast<const float4*>(gv + (size_t)gi * HD + lane * 4);
    acc.x += x.x; acc.y += x.y; acc.z += x.z; acc.w += x.w;
  }
  float* pp = pool + (size_t)cur * HD + lane * 4;
  atomicAdd(pp + 0, acc.x); atomicAdd(pp + 1, acc.y);
  atomicAdd(pp + 2, acc.z); atomicAdd(pp + 3, acc.w);
}

// ---------------------------------------------------------------------------
// finalize: build t_in = [root | tree_mean | inter_mean] (768) and g_in (256)
// per molecule, run 4 small GEMV-batches (Tm,Tv,Gm,Gv), reparameterize, KL.
// 8 molecules per block; thread = (matrix m = t>>6, column l = t&63);
// 8-row register blocking amortizes W reads.
// ---------------------------------------------------------------------------
#define RB 8
__global__ __launch_bounds__(256) void finalize(
    const float* __restrict__ root, const float* __restrict__ tsum,
    const float* __restrict__ isum, const float* __restrict__ gpool,
    const float* __restrict__ cnt,
    const float* __restrict__ Tm_w, const float* __restrict__ Tm_b,
    const float* __restrict__ Tv_w, const float* __restrict__ Tv_b,
    const float* __restrict__ Gm_w, const float* __restrict__ Gm_b,
    const float* __restrict__ Gv_w, const float* __restrict__ Gv_b,
    const float* __restrict__ eps_t, const float* __restrict__ eps_g,
    float* __restrict__ out, float* __restrict__ kl_acc)
{
  __shared__ float xs[RB][1024];   // [0:768) = t_in, [768:1024) = g_in
  __shared__ float zs[RB][256];    // raw linear outputs, cols: Tm|Tv|Gm|Gv
  __shared__ float wsum[4];

  int b0 = blockIdx.x * RB;
  int t = threadIdx.x;

  #pragma unroll
  for (int r = 0; r < RB; ++r) {
    int b = b0 + r;
    float inv = 1.0f / fmaxf(cnt[b], 1.0f);
    xs[r][t]       = root[(size_t)b * HD + t];
    xs[r][256 + t] = tsum[(size_t)b * HD + t] * inv;
    xs[r][512 + t] = isum[(size_t)b * HD + t] * inv;
    xs[r][768 + t] = gpool[(size_t)b * HD + t];
  }
  __syncthreads();

  int m = t >> 6, l = t & 63;
  const float* W; float bias; int K, xoff;
  if (m == 0)      { W = Tm_w; bias = Tm_b[l]; K = 768; xoff = 0;   }
  else if (m == 1) { W = Tv_w; bias = Tv_b[l]; K = 768; xoff = 0;   }
  else if (m == 2) { W = Gm_w; bias = Gm_b[l]; K = 256; xoff = 768; }
  else             { W = Gv_w; bias = Gv_b[l]; K = 256; xoff = 768; }

  float acc[RB];
  #pragma unroll
  for (int r = 0; r < RB; ++r) acc[r] = bias;

  for (int k = 0; k < K; k += 4) {
    float w0 = W[(k + 0) * LD + l];
    float w1 = W[(k + 1) * LD + l];
    float w2 = W[(k + 2) * LD + l];
    float w3 = W[(k + 3) * LD + l];
    #pragma unroll
    for (int r = 0; r < RB; ++r) {
      float4 x = *reinterpret_cast<const float4*>(&xs[r][xoff + k]);
      acc[r] = fmaf(x.x, w0, acc[r]);
      acc[r] = fmaf(x.y, w1, acc[r]);
      acc[r] = fmaf(x.z, w2, acc[r]);
      acc[r] = fmaf(x.w, w3, acc[r]);
    }
  }

  #pragma unroll
  for (int r = 0; r < RB; ++r) zs[r][t] = acc[r];
  __syncthreads();

  // epilogue: 8 molecules x 128 outputs = 1024 -> 4 per thread
  float klp = 0.f;
  #pragma unroll
  for (int i = t; i < RB * 128; i += 256) {
    int r = i >> 7;
    int j = i & 127;            // 0..63 tree, 64..127 graph
    int which = j >> 6, l2 = j & 63;
    float zm  = zs[r][which * 128 + l2];
    float zvr = zs[r][which * 128 + 64 + l2];
    float lv  = -fabsf(zvr);
    float elv = expf(lv);
    int b = b0 + r;
    float e = which ? eps_g[(size_t)b * LD + l2] : eps_t[(size_t)b * LD + l2];
    out[(size_t)b * 128 + j] = zm + sqrtf(elv) * e;
    klp += 1.0f + lv - zm * zm - elv;
  }

  // block reduction of KL partial
  #pragma unroll
  for (int off = 32; off > 0; off >>= 1) klp += __shfl_down(klp, off, 64);
  if ((t & 63) == 0) wsum[t >> 6] = klp;
  __syncthreads();
  if (t == 0) atomicAdd(kl_acc, wsum[0] + wsum[1] + wsum[2] + wsum[3]);
}

__global__ void kl_finish(const float* __restrict__ kl_acc, float* __restrict__ out_kl) {
  *out_kl = (*kl_acc) * (-0.5f / 4096.0f);
}

// ---------------------------------------------------------------------------
extern "C" void kernel_launch(void* const* d_in, const int* in_sizes, int n_in,
                              void* d_out, int out_size, void* d_ws, size_t ws_size,
                              hipStream_t stream) {
  const float* root  = (const float*)d_in[0];
  const float* tree  = (const float*)d_in[1];
  const float* inter = (const float*)d_in[2];
  const float* graph = (const float*)d_in[3];
  const float* Tm_w  = (const float*)d_in[4];
  const float* Tm_b  = (const float*)d_in[5];
  const float* Tv_w  = (const float*)d_in[6];
  const float* Tv_b  = (const float*)d_in[7];
  const float* Gm_w  = (const float*)d_in[8];
  const float* Gm_b  = (const float*)d_in[9];
  const float* Gv_w  = (const float*)d_in[10];
  const float* Gv_b  = (const float*)d_in[11];
  const float* eps_t = (const float*)d_in[12];
  const float* eps_g = (const float*)d_in[13];
  const int*   tseg  = (const int*)d_in[14];
  const int*   aidx  = (const int*)d_in[15];
  const int*   aseg  = (const int*)d_in[16];
  float* out = (float*)d_out;

  int B      = in_sizes[0] / HD;    // 4096
  int n_tree = in_sizes[1] / HD;    // 400000
  int n_anch = in_sizes[15];        // 200000

  // workspace layout
  float* tsum  = (float*)d_ws;                  // B*H
  float* isum  = tsum + (size_t)B * HD;         // B*H
  float* gpool = isum + (size_t)B * HD;         // B*H
  float* cnt   = gpool + (size_t)B * HD;        // B
  float* klac  = cnt + B;                       // 1
  int zn = 3 * B * HD + B + 1;

  zero_ws<<<512, 256, 0, stream>>>((float*)d_ws, zn);

  {
    const int blocks = 2048;
    int waves = blocks * 4;
    int rpw = (n_tree + waves - 1) / waves;
    seg_pair_sum<<<blocks, 256, 0, stream>>>(tree, inter, tseg, n_tree, rpw,
                                             tsum, isum, cnt);
  }
  {
    const int blocks = 1024;
    int waves = blocks * 4;
    int rpw = (n_anch + waves - 1) / waves;
    anchor_pool<<<blocks, 256, 0, stream>>>(graph, aidx, aseg, n_anch, rpw, gpool);
  }

  finalize<<<B / RB, 256, 0, stream>>>(root, tsum, isum, gpool, cnt,
                                       Tm_w, Tm_b, Tv_w, Tv_b,
                                       Gm_w, Gm_b, Gv_w, Gv_b,
                                       eps_t, eps_g, out, klac);

  kl_finish<<<1, 1, 0, stream>>>(klac, out + (size_t)B * 128);
}